// Round 13
// baseline (31.910 us; speedup 1.0000x reference)
//
#include <hip/hip_runtime.h>

// GatedBlock: B=16, C=128, T=64, F=128, S=62, dilation=2, fp32 in/out.
// out[b,c,s,f] = (tanh(x0*wt0+x1*wt1+bt) * sigmoid(x0*ws0+x1*ws1+bs)
//                 + sum_t x[b,c,t,f]*w_res[s,t] + b_res[s]) * w_out[c] + b_out[c]
//
// Round 13 = round 12 (2 channels/block, software-pipelined) with the macro
// scoping bug fixed: epilogue is a device lambda (captures acc & geometry,
// takes per-channel scalars as args). Design unchanged:
//  - grid 1024; block handles bc0=2*blockIdx, bc1=bc0+1; w_res A-frags staged
//    once, reused for both halves.
//  - x(bc1) loads issued between MFMA-0 and epilogue-0 (latency hides under
//    epilogue-0's VALU/trans); ds_writes deferred past the barrier.
//  - per-half structure identical to r7 (the only spill-clean config).

typedef __attribute__((ext_vector_type(8)))  short short8;
typedef __attribute__((ext_vector_type(4)))  float f32x4;
typedef __attribute__((ext_vector_type(4)))  int   i32x4;
typedef __attribute__((ext_vector_type(2)))  int   i32x2;

constexpr int Bc = 16, Cc = 128, Tc = 64, Fc = 128, Sc = 62, DIL = 2;
constexpr int LDSTW    = 72;                  // bf16 elems per xT f-row
constexpr int XT_BYTES = Fc * LDSTW * 2;      // 18432
constexpr int A_BYTES  = 8 * 64 * 16;         // 8192
constexpr int LDS_TOT  = XT_BYTES + A_BYTES;  // 26624

__device__ inline unsigned cvt_pk_bf16(float lo, float hi) {
    unsigned r;
    asm("v_cvt_pk_bf16_f32 %0, %1, %2" : "=v"(r) : "v"(lo), "v"(hi));
    return r;   // low16 = bf16(lo), high16 = bf16(hi), RNE
}

__device__ inline float bf16_lo(int u) { return __uint_as_float(((unsigned)u) << 16); }
__device__ inline float bf16_hi(int u) { return __uint_as_float(((unsigned)u) & 0xFFFF0000u); }

__global__ __launch_bounds__(256, 5)
void gated_mfma_kernel(const float* __restrict__ x,
                       const float* __restrict__ w_tanh,
                       const float* __restrict__ b_tanh,
                       const float* __restrict__ w_sig,
                       const float* __restrict__ b_sig,
                       const float* __restrict__ w_out,
                       const float* __restrict__ b_out,
                       const float* __restrict__ w_res,
                       const float* __restrict__ b_res,
                       float* __restrict__ out)
{
    __shared__ i32x4 smem[LDS_TOT / 16];
    char* lds_base = (char*)smem;              // xT: [0, 18432)
    char* lds_a    = lds_base + XT_BYTES;      // A-frags: [18432, 26624)

    const int bc0  = blockIdx.x * 2;           // first (b,c) pair
    const int bc1  = bc0 + 1;
    const int c0   = bc0 & (Cc - 1);
    const int c1   = bc1 & (Cc - 1);
    const int tid  = threadIdx.x;
    const int lane = tid & 63;
    const int w    = tid >> 6;                 // wave 0..3 -> col-tiles 2w,2w+1
    const int g    = lane >> 4;                // lane group 0..3
    const int r16  = lane & 15;

    const int fq = tid & 31;                   // f = 4*fq .. 4*fq+3
    const int tg = tid >> 5;                   // t = 8*tg .. 8*tg+7
    const int tsw  = 8 * (tg ^ (fq & 3));      // xT write swizzle
    const int col0 = 32 * w + r16;
    const int swz8 = 8 * (g ^ (r16 >> 2));     // B-frag t-swizzle bits
    const int sw8  = 8 * (r16 >> 2);           // epilogue tap swizzle bits

    const float* xp0 = x + (size_t)bc0 * (Tc * Fc);
    const float* xp1 = x + (size_t)bc1 * (Tc * Fc);

    f32x4 acc[4][2];

    // epilogue helper: gate from LDS bf16 taps + acc -> out (channel scalars as args)
    auto epilogue = [&](float* op, float wt0, float wt1, float bt,
                        float ws0, float ws1, float bs, float wo, float bo) {
#pragma unroll
        for (int rt = 0; rt < 4; ++rt) {
            const int r0 = 16 * rt + 4 * g;
#pragma unroll
            for (int ct = 0; ct < 2; ++ct) {
                const int col = col0 + 16 * ct;
                const i32x2 d1 = *(const i32x2*)(lds_base + (col * LDSTW + (r0 ^ sw8)) * 2);
                const i32x2 d2 = *(const i32x2*)(lds_base + (col * LDSTW + ((r0 + 4) ^ sw8)) * 2);
                const float t[6] = { bf16_lo(d1.x), bf16_hi(d1.x),
                                     bf16_lo(d1.y), bf16_hi(d1.y),
                                     bf16_lo(d2.x), bf16_hi(d2.x) };
#pragma unroll
                for (int reg = 0; reg < 4; ++reg) {
                    if (r0 + reg < Sc) {
                        const float xa = t[reg];
                        const float xb = t[reg + 2];
                        const float xt  = fmaf(xa, wt0, fmaf(xb, wt1, bt));
                        const float xsg = fmaf(xa, ws0, fmaf(xb, ws1, bs));
                        const float e2  = __expf(2.0f * xt);
                        const float em  = __expf(-xsg);
                        const float gate = (e2 - 1.0f) *
                            __builtin_amdgcn_rcpf((e2 + 1.0f) * (1.0f + em));
                        op[(r0 + reg) * Fc + col] = fmaf(gate + acc[rt][ct][reg], wo, bo);
                    }
                }
            }
        }
    };

    auto acc_init = [&]() {
#pragma unroll
        for (int rt = 0; rt < 4; ++rt) {
            f32x4 bv;
#pragma unroll
            for (int j = 0; j < 4; ++j) {
                const int idx = 16 * rt + 4 * g + j;
                bv[j] = b_res[idx < Sc ? idx : Sc - 1];
            }
            acc[rt][0] = bv;
            acc[rt][1] = bv;
        }
    };

    auto mfma_block = [&]() {
        short8 A[4][2];
#pragma unroll
        for (int rt = 0; rt < 4; ++rt)
#pragma unroll
            for (int kt = 0; kt < 2; ++kt)
                A[rt][kt] = *(const short8*)(lds_a + ((rt * 2 + kt) * 64 + lane) * 16);
#pragma unroll
        for (int kt = 0; kt < 2; ++kt) {
            short8 Bf[2];
#pragma unroll
            for (int ct = 0; ct < 2; ++ct)
                Bf[ct] = *(const short8*)(lds_base +
                            ((col0 + 16 * ct) * LDSTW + 32 * kt + swz8) * 2);
#pragma unroll
            for (int rt = 0; rt < 4; ++rt)
#pragma unroll
                for (int ct = 0; ct < 2; ++ct)
                    acc[rt][ct] = __builtin_amdgcn_mfma_f32_16x16x32_bf16(
                        A[rt][kt], Bf[ct], acc[rt][ct], 0, 0, 0);
        }
    };

    // ================= PHASE A: stage half 0 + shared A-frags =================
    {
        f32x4 v[8];
#pragma unroll
        for (int u = 0; u < 8; ++u)
            v[u] = *(const f32x4*)(xp0 + (8 * tg + u) * Fc + 4 * fq);

        // stage w_res as bf16 A-fragments (explicit slot, verified r7)
#pragma unroll
        for (int i = 0; i < 2; ++i) {
            const int u   = tid + 256 * i;     // 0..511
            const int row = u >> 3;
            const int k8  = u & 7;
            f32x4 a0 = f32x4{0.f, 0.f, 0.f, 0.f};
            f32x4 a1 = f32x4{0.f, 0.f, 0.f, 0.f};
            if (row < Sc) {
                const float* wr = w_res + row * Tc + 8 * k8;
                a0 = *(const f32x4*)(wr);
                a1 = *(const f32x4*)(wr + 4);
            }
            const unsigned p0 = cvt_pk_bf16(a0.x, a0.y);
            const unsigned p1 = cvt_pk_bf16(a0.z, a0.w);
            const unsigned p2 = cvt_pk_bf16(a1.x, a1.y);
            const unsigned p3 = cvt_pk_bf16(a1.z, a1.w);
            const int slot = ((row >> 4) * 2 + (k8 >> 2)) * 64 + (k8 & 3) * 16 + (row & 15);
            *(i32x4*)(lds_a + slot * 16) = i32x4{(int)p0, (int)p1, (int)p2, (int)p3};
        }

        // xT writes (half 0)
#pragma unroll
        for (int fj = 0; fj < 4; ++fj) {
            const unsigned p0 = cvt_pk_bf16(v[0][fj], v[1][fj]);
            const unsigned p1 = cvt_pk_bf16(v[2][fj], v[3][fj]);
            const unsigned p2 = cvt_pk_bf16(v[4][fj], v[5][fj]);
            const unsigned p3 = cvt_pk_bf16(v[6][fj], v[7][fj]);
            *(i32x4*)(lds_base + ((4 * fq + fj) * LDSTW + tsw) * 2) =
                i32x4{(int)p0, (int)p1, (int)p2, (int)p3};
        }
    }

    acc_init();
    __syncthreads();

    // ================= PHASE B: MFMA 0 + prefetch x1 + epilogue 0 =============
    mfma_block();

    // prefetch half-1 x into registers; latency hides under epilogue 0
    f32x4 v1[8];
#pragma unroll
    for (int u = 0; u < 8; ++u)
        v1[u] = *(const f32x4*)(xp1 + (8 * tg + u) * Fc + 4 * fq);

    epilogue(out + (size_t)bc0 * (Sc * Fc),
             w_tanh[2 * c0 + 0], w_tanh[2 * c0 + 1], b_tanh[c0],
             w_sig[2 * c0 + 0],  w_sig[2 * c0 + 1],  b_sig[c0],
             w_out[c0], b_out[c0]);

    __syncthreads();   // all epilogue-0 xT reads done before overwrite

    // ================= PHASE C: stage half 1 =================================
#pragma unroll
    for (int fj = 0; fj < 4; ++fj) {
        const unsigned p0 = cvt_pk_bf16(v1[0][fj], v1[1][fj]);
        const unsigned p1 = cvt_pk_bf16(v1[2][fj], v1[3][fj]);
        const unsigned p2 = cvt_pk_bf16(v1[4][fj], v1[5][fj]);
        const unsigned p3 = cvt_pk_bf16(v1[6][fj], v1[7][fj]);
        *(i32x4*)(lds_base + ((4 * fq + fj) * LDSTW + tsw) * 2) =
            i32x4{(int)p0, (int)p1, (int)p2, (int)p3};
    }

    acc_init();
    __syncthreads();

    // ================= PHASE D: MFMA 1 + epilogue 1 ===========================
    mfma_block();

    epilogue(out + (size_t)bc1 * (Sc * Fc),
             w_tanh[2 * c1 + 0], w_tanh[2 * c1 + 1], b_tanh[c1],
             w_sig[2 * c1 + 0],  w_sig[2 * c1 + 1],  b_sig[c1],
             w_out[c1], b_out[c1]);
}

extern "C" void kernel_launch(void* const* d_in, const int* in_sizes, int n_in,
                              void* d_out, int out_size, void* d_ws, size_t ws_size,
                              hipStream_t stream)
{
    const float* x      = (const float*)d_in[0];
    const float* w_tanh = (const float*)d_in[1];
    const float* b_tanh = (const float*)d_in[2];
    const float* w_sig  = (const float*)d_in[3];
    const float* b_sig  = (const float*)d_in[4];
    const float* w_out  = (const float*)d_in[5];
    const float* b_out  = (const float*)d_in[6];
    const float* w_res  = (const float*)d_in[7];
    const float* b_res  = (const float*)d_in[8];
    // d_in[9] = dilation (==2) -> compile-time DIL.

    float* out = (float*)d_out;

    gated_mfma_kernel<<<(Bc * Cc) / 2, 256, 0, stream>>>(
        x, w_tanh, b_tanh, w_sig, b_sig, w_out, b_out, w_res, b_res, out);
}

// Round 14
// 27.515 us; speedup vs baseline: 1.1597x; 1.1597x over previous
//
#include <hip/hip_runtime.h>

// GatedBlock: B=16, C=128, T=64, F=128, S=62, dilation=2, fp32 in/out.
// out[b,c,s,f] = (tanh(x0*wt0+x1*wt1+bt) * sigmoid(x0*ws0+x1*ws1+bs)
//                 + sum_t x[b,c,t,f]*w_res[s,t] + b_res[s]) * w_out[c] + b_out[c]
//
// Round 14 = FINAL: verbatim round 7/11 (27.55us, the measured best).
// Exploration record: r8 (occupancy 8/CU) -> spills; r9 (ct-split, (256,6)) ->
// spills; r10 (operand swap) -> spills + L2-miss taps; r13 (2-ch pipeline) ->
// lost TLP (31.9us). The hardware already overlaps one block's stage with
// another block's compute at 5 blocks/CU; explicit pipelining only removed
// scheduling freedom. This structure is the empirical optimum.

typedef __attribute__((ext_vector_type(8)))  short short8;
typedef __attribute__((ext_vector_type(4)))  float f32x4;
typedef __attribute__((ext_vector_type(4)))  int   i32x4;
typedef __attribute__((ext_vector_type(2)))  int   i32x2;

constexpr int Bc = 16, Cc = 128, Tc = 64, Fc = 128, Sc = 62, DIL = 2;
constexpr int LDSTW    = 72;                  // bf16 elems per xT f-row (mult of 8)
constexpr int XT_BYTES = Fc * LDSTW * 2;      // 18432
constexpr int A_BYTES  = 8 * 64 * 16;         // 8192
constexpr int LDS_TOT  = XT_BYTES + A_BYTES;  // 26624

__device__ inline unsigned cvt_pk_bf16(float lo, float hi) {
    unsigned r;
    asm("v_cvt_pk_bf16_f32 %0, %1, %2" : "=v"(r) : "v"(lo), "v"(hi));
    return r;   // low16 = bf16(lo), high16 = bf16(hi), RNE
}

__device__ inline float bf16_lo(int u) { return __uint_as_float(((unsigned)u) << 16); }
__device__ inline float bf16_hi(int u) { return __uint_as_float(((unsigned)u) & 0xFFFF0000u); }

__global__ __launch_bounds__(256, 5)
void gated_mfma_kernel(const float* __restrict__ x,
                       const float* __restrict__ w_tanh,
                       const float* __restrict__ b_tanh,
                       const float* __restrict__ w_sig,
                       const float* __restrict__ b_sig,
                       const float* __restrict__ w_out,
                       const float* __restrict__ b_out,
                       const float* __restrict__ w_res,
                       const float* __restrict__ b_res,
                       float* __restrict__ out)
{
    __shared__ i32x4 smem[LDS_TOT / 16];
    char* lds_base = (char*)smem;              // xT: [0, 18432)
    char* lds_a    = lds_base + XT_BYTES;      // A-frags: [18432, 26624)

    const int bc   = blockIdx.x;               // (b,c) pair
    const int c    = bc & (Cc - 1);
    const int tid  = threadIdx.x;
    const int lane = tid & 63;
    const int w    = tid >> 6;                 // wave 0..3 -> col-tiles 2w,2w+1
    const int g    = lane >> 4;                // lane group 0..3
    const int r16  = lane & 15;

    const float wt0 = w_tanh[2 * c + 0], wt1 = w_tanh[2 * c + 1], bt = b_tanh[c];
    const float ws0 = w_sig[2 * c + 0],  ws1 = w_sig[2 * c + 1],  bs = b_sig[c];
    const float wo  = w_out[c],          bo  = b_out[c];

    // ---- stage x: thread (fq,tg) loads 8t x 4f block, coalesced dwordx4 ----
    const int fq = tid & 31;                   // f = 4*fq .. 4*fq+3
    const int tg = tid >> 5;                   // t = 8*tg .. 8*tg+7
    const float* xp = x + (size_t)bc * (Tc * Fc);
    f32x4 v[8];
#pragma unroll
    for (int u = 0; u < 8; ++u)
        v[u] = *(const f32x4*)(xp + (8 * tg + u) * Fc + 4 * fq);

    // ---- stage w_res as bf16 A-fragments (explicit slot, verified) ----
    // unit u=(row=u>>3, k8=u&7) holds w_res[row][8k8..8k8+7];
    // slot = (2*(row>>4) + (k8>>2))*64 + (k8&3)*16 + (row&15); read is linear.
#pragma unroll
    for (int i = 0; i < 2; ++i) {
        const int u   = tid + 256 * i;         // 0..511
        const int row = u >> 3;
        const int k8  = u & 7;
        f32x4 a0 = f32x4{0.f, 0.f, 0.f, 0.f};
        f32x4 a1 = f32x4{0.f, 0.f, 0.f, 0.f};
        if (row < Sc) {
            const float* wr = w_res + row * Tc + 8 * k8;
            a0 = *(const f32x4*)(wr);
            a1 = *(const f32x4*)(wr + 4);
        }
        const unsigned p0 = cvt_pk_bf16(a0.x, a0.y);
        const unsigned p1 = cvt_pk_bf16(a0.z, a0.w);
        const unsigned p2 = cvt_pk_bf16(a1.x, a1.y);
        const unsigned p3 = cvt_pk_bf16(a1.z, a1.w);
        const int slot = ((row >> 4) * 2 + (k8 >> 2)) * 64 + (k8 & 3) * 16 + (row & 15);
        *(i32x4*)(lds_a + slot * 16) = i32x4{(int)p0, (int)p1, (int)p2, (int)p3};
    }

    // ---- xT writes: 4 x ds_write_b128, swizzle t~ = t ^ 8*((f>>2)&3) ----
    const int tsw = 8 * (tg ^ (fq & 3));
#pragma unroll
    for (int fj = 0; fj < 4; ++fj) {
        const unsigned p0 = cvt_pk_bf16(v[0][fj], v[1][fj]);
        const unsigned p1 = cvt_pk_bf16(v[2][fj], v[3][fj]);
        const unsigned p2 = cvt_pk_bf16(v[4][fj], v[5][fj]);
        const unsigned p3 = cvt_pk_bf16(v[6][fj], v[7][fj]);
        *(i32x4*)(lds_base + ((4 * fq + fj) * LDSTW + tsw) * 2) =
            i32x4{(int)p0, (int)p1, (int)p2, (int)p3};
    }

    // ---- acc init = b_res[row] (C-operand); clamp tail (rows>=62 masked) ----
    f32x4 acc[4][2];
#pragma unroll
    for (int rt = 0; rt < 4; ++rt) {
        f32x4 bv;
#pragma unroll
        for (int j = 0; j < 4; ++j) {
            const int idx = 16 * rt + 4 * g + j;
            bv[j] = b_res[idx < Sc ? idx : Sc - 1];
        }
        acc[rt][0] = bv;
        acc[rt][1] = bv;
    }

    __syncthreads();

    // ---- A fragments from LDS (linear b128, conflict-free) ----
    short8 A[4][2];
#pragma unroll
    for (int rt = 0; rt < 4; ++rt)
#pragma unroll
        for (int kt = 0; kt < 2; ++kt)
            A[rt][kt] = *(const short8*)(lds_a + ((rt * 2 + kt) * 64 + lane) * 16);

    // ---- B frags: one b128 each; MFMA 2kt x 2ct x 4rt ----
    const int col0 = 32 * w + r16;
    const int swz8 = 8 * (g ^ (r16 >> 2));     // sw(col) = r16>>2 for all our cols
#pragma unroll
    for (int kt = 0; kt < 2; ++kt) {
        short8 Bf[2];
#pragma unroll
        for (int ct = 0; ct < 2; ++ct)
            Bf[ct] = *(const short8*)(lds_base +
                        ((col0 + 16 * ct) * LDSTW + 32 * kt + swz8) * 2);
#pragma unroll
        for (int rt = 0; rt < 4; ++rt)
#pragma unroll
            for (int ct = 0; ct < 2; ++ct)
                acc[rt][ct] = __builtin_amdgcn_mfma_f32_16x16x32_bf16(
                    A[rt][kt], Bf[ct], acc[rt][ct], 0, 0, 0);
    }

    // ---- epilogue: taps via 2 x ds_read_b64 bf16; gate; store ----
    const int sw8 = 8 * (r16 >> 2);            // swizzle bits for tap addressing
    float* op = out + (size_t)bc * (Sc * Fc);
#pragma unroll
    for (int rt = 0; rt < 4; ++rt) {
        const int r0 = 16 * rt + 4 * g;
#pragma unroll
        for (int ct = 0; ct < 2; ++ct) {
            const int col = col0 + 16 * ct;
            const i32x2 d1 = *(const i32x2*)(lds_base + (col * LDSTW + (r0 ^ sw8)) * 2);
            const i32x2 d2 = *(const i32x2*)(lds_base + (col * LDSTW + ((r0 + 4) ^ sw8)) * 2);
            const float t0 = bf16_lo(d1.x);    // x[r0]
            const float t1 = bf16_hi(d1.x);    // x[r0+1]
            const float t2 = bf16_lo(d1.y);    // x[r0+2]
            const float t3 = bf16_hi(d1.y);    // x[r0+3]
            const float t4 = bf16_lo(d2.x);    // x[r0+4] (garbage if r0+4>=64: masked)
            const float t5 = bf16_hi(d2.x);    // x[r0+5]

#define GATE_OUT(reg, xa, xb)                                                     \
            if (r0 + (reg) < Sc) {                                                \
                const float xt  = fmaf((xa), wt0, fmaf((xb), wt1, bt));           \
                const float xsg = fmaf((xa), ws0, fmaf((xb), ws1, bs));           \
                const float e2  = __expf(2.0f * xt);                              \
                const float em  = __expf(-xsg);                                   \
                const float gate = (e2 - 1.0f) *                                  \
                    __builtin_amdgcn_rcpf((e2 + 1.0f) * (1.0f + em));             \
                op[(r0 + (reg)) * Fc + col] =                                     \
                    fmaf(gate + acc[rt][ct][reg], wo, bo);                        \
            }
            GATE_OUT(0, t0, t2)
            GATE_OUT(1, t1, t3)
            GATE_OUT(2, t2, t4)
            GATE_OUT(3, t3, t5)
#undef GATE_OUT
        }
    }
}

extern "C" void kernel_launch(void* const* d_in, const int* in_sizes, int n_in,
                              void* d_out, int out_size, void* d_ws, size_t ws_size,
                              hipStream_t stream)
{
    const float* x      = (const float*)d_in[0];
    const float* w_tanh = (const float*)d_in[1];
    const float* b_tanh = (const float*)d_in[2];
    const float* w_sig  = (const float*)d_in[3];
    const float* b_sig  = (const float*)d_in[4];
    const float* w_out  = (const float*)d_in[5];
    const float* b_out  = (const float*)d_in[6];
    const float* w_res  = (const float*)d_in[7];
    const float* b_res  = (const float*)d_in[8];
    // d_in[9] = dilation (==2) -> compile-time DIL.

    float* out = (float*)d_out;

    gated_mfma_kernel<<<Bc * Cc, 256, 0, stream>>>(
        x, w_tanh, b_tanh, w_sig, b_sig, w_out, b_out, w_res, b_res, out);
}